// Round 1
// 793.570 us; speedup vs baseline: 1.0648x; 1.0648x over previous
//
#include <hip/hip_runtime.h>

typedef unsigned short u16;
typedef __bf16 bf16x8 __attribute__((ext_vector_type(8)));
typedef float f32x4 __attribute__((ext_vector_type(4)));

#define MFMA_BF16(a,b,c) __builtin_amdgcn_mfma_f32_16x16x32_bf16((a),(b),(c),0,0,0)

// ---- constants ----
#define Bc 2
#define Sc 2048
#define Dc 1024
#define Hc 16
#define Dh 64
#define Mrows (Bc*Sc)          // 4096

// ws element offsets (u16 units)
#define OFF_QB   0u
#define OFF_KB   4194304u
#define OFF_VB   8388608u
#define OFF_WQB  12582912u
#define OFF_WKB  13631488u
#define OFF_WVB  14680064u
#define OFF_WOB  15728640u
#define OFF_QP   16777216u
#define OFF_KP   20971520u
#define OFF_VP   25165824u
#define OFF_VT   29360128u
#define OFF_OH   33554432u
// total = 37748736 u16 = 75,497,472 bytes of ws

__device__ __forceinline__ u16 f32_to_bf16(float f) {
  unsigned u = __builtin_bit_cast(unsigned, f);
  u += 0x7FFFu + ((u >> 16) & 1u);
  return (u16)(u >> 16);
}
__device__ __forceinline__ float bf16_to_f32(u16 x) {
  return __builtin_bit_cast(float, ((unsigned)x) << 16);
}

// ---------------- fp32 -> bf16 conversion of all inputs ----------------
__global__ __launch_bounds__(256) void cvt_all(
    const float* __restrict__ q, const float* __restrict__ k, const float* __restrict__ v,
    const float* __restrict__ wq, const float* __restrict__ wk,
    const float* __restrict__ wv, const float* __restrict__ wo,
    u16* __restrict__ ws)
{
  int y = blockIdx.y;
  const float* src; u16* dst; int n;
  if (y < 3) {
    src = (y == 0) ? q : (y == 1) ? k : v;
    dst = ws + (unsigned)y * 4194304u;
    n = 4194304;
  } else {
    src = (y == 3) ? wq : (y == 4) ? wk : (y == 5) ? wv : wo;
    dst = ws + OFF_WQB + (unsigned)(y - 3) * 1048576u;
    n = 1048576;
  }
  int i = (blockIdx.x * 256 + threadIdx.x) * 8;
  if (i >= n) return;
  float4 f0 = *(const float4*)(src + i);
  float4 f1 = *(const float4*)(src + i + 4);
  u16 o[8];
  o[0] = f32_to_bf16(f0.x); o[1] = f32_to_bf16(f0.y);
  o[2] = f32_to_bf16(f0.z); o[3] = f32_to_bf16(f0.w);
  o[4] = f32_to_bf16(f1.x); o[5] = f32_to_bf16(f1.y);
  o[6] = f32_to_bf16(f1.z); o[7] = f32_to_bf16(f1.w);
  *(uint4*)(dst + i) = *(uint4*)o;
}

// ---------------- 128x128 NT GEMM body (C = X @ W^T + bias) ----------------
__device__ __forceinline__ void gemm128_body(
    const u16* __restrict__ X, const u16* __restrict__ W, const float* __restrict__ bias,
    u16* __restrict__ out_bf, float* __restrict__ out_f,
    u16* As, u16* Bs, int m0, int n0)
{
  int tid = threadIdx.x;
  int lane = tid & 63, w = tid >> 6;
  int wr = w >> 1, wc = w & 1;
  int qd = lane >> 4, ln = lane & 15;

  f32x4 acc[4][4];
#pragma unroll
  for (int i = 0; i < 4; i++)
#pragma unroll
    for (int j = 0; j < 4; j++) acc[i][j] = f32x4{0.f, 0.f, 0.f, 0.f};

  int sr = tid >> 2;          // 0..63
  int sc = (tid & 3) * 8;     // 0,8,16,24
  const u16* Xa = X + (size_t)(m0 + sr) * 1024 + sc;
  const u16* Xb = X + (size_t)(m0 + sr + 64) * 1024 + sc;
  const u16* Wa = W + (size_t)(n0 + sr) * 1024 + sc;
  const u16* Wb = W + (size_t)(n0 + sr + 64) * 1024 + sc;

  for (int k0 = 0; k0 < 1024; k0 += 32) {
    __syncthreads();
    *(uint4*)&As[sr * 40 + sc]        = *(const uint4*)(Xa + k0);
    *(uint4*)&As[(sr + 64) * 40 + sc] = *(const uint4*)(Xb + k0);
    *(uint4*)&Bs[sr * 40 + sc]        = *(const uint4*)(Wa + k0);
    *(uint4*)&Bs[(sr + 64) * 40 + sc] = *(const uint4*)(Wb + k0);
    __syncthreads();
    bf16x8 af[4], bfr[4];
#pragma unroll
    for (int i = 0; i < 4; i++)
      af[i] = *(const bf16x8*)&As[(wr * 64 + i * 16 + ln) * 40 + qd * 8];
#pragma unroll
    for (int j = 0; j < 4; j++)
      bfr[j] = *(const bf16x8*)&Bs[(wc * 64 + j * 16 + ln) * 40 + qd * 8];
#pragma unroll
    for (int i = 0; i < 4; i++)
#pragma unroll
      for (int j = 0; j < 4; j++)
        acc[i][j] = MFMA_BF16(af[i], bfr[j], acc[i][j]);
  }

#pragma unroll
  for (int i = 0; i < 4; i++) {
#pragma unroll
    for (int j = 0; j < 4; j++) {
      int col = n0 + wc * 64 + j * 16 + ln;
      float bv = bias[col];
#pragma unroll
      for (int r = 0; r < 4; r++) {
        int row = m0 + wr * 64 + i * 16 + qd * 4 + r;
        float val = acc[i][j][r] + bv;
        if (out_bf) out_bf[(size_t)row * 1024 + col] = f32_to_bf16(val);
        else        out_f[(size_t)row * 1024 + col]  = val;
      }
    }
  }
}

__global__ __launch_bounds__(256) void qkv_gemm(
    const u16* __restrict__ xq, const u16* __restrict__ xk, const u16* __restrict__ xv,
    const u16* __restrict__ wq, const u16* __restrict__ wk, const u16* __restrict__ wv,
    const float* __restrict__ bq, const float* __restrict__ bk, const float* __restrict__ bv,
    u16* __restrict__ Qp, u16* __restrict__ Kp, u16* __restrict__ Vp)
{
  __shared__ __attribute__((aligned(16))) u16 As[128 * 40];
  __shared__ __attribute__((aligned(16))) u16 Bs[128 * 40];
  const u16 *X, *W; const float* bias; u16* out;
  int z = blockIdx.z;
  if (z == 0)      { X = xq; W = wq; bias = bq; out = Qp; }
  else if (z == 1) { X = xk; W = wk; bias = bk; out = Kp; }
  else             { X = xv; W = wv; bias = bv; out = Vp; }
  gemm128_body(X, W, bias, out, nullptr, As, Bs, blockIdx.y * 128, blockIdx.x * 128);
}

__global__ __launch_bounds__(256) void out_gemm(
    const u16* __restrict__ Oh, const u16* __restrict__ Wo, const float* __restrict__ bo,
    float* __restrict__ out)
{
  __shared__ __attribute__((aligned(16))) u16 As[128 * 40];
  __shared__ __attribute__((aligned(16))) u16 Bs[128 * 40];
  gemm128_body(Oh, Wo, bo, nullptr, out, As, Bs, blockIdx.y * 128, blockIdx.x * 128);
}

// ---------------- V transpose: Vp [B,S,D] -> Vt [B*H, Dh, S] ----------------
__global__ __launch_bounds__(256) void transpose_v(const u16* __restrict__ Vp, u16* __restrict__ Vt)
{
  __shared__ __attribute__((aligned(16))) u16 T[64 * 72];
  int tid = threadIdx.x;
  int st = blockIdx.x;    // s tile 0..31
  int bh = blockIdx.y;    // 0..31
  int b = bh >> 4, h = bh & 15;
  int r0 = tid >> 3, c0 = (tid & 7) * 8;
  const u16* src = Vp + (size_t)(b * Sc + st * 64) * Dc + h * 64;
  *(uint4*)&T[r0 * 72 + c0]        = *(const uint4*)&src[(size_t)r0 * Dc + c0];
  *(uint4*)&T[(r0 + 32) * 72 + c0] = *(const uint4*)&src[(size_t)(r0 + 32) * Dc + c0];
  __syncthreads();
  u16* dst = Vt + (size_t)bh * 64 * Sc + st * 64;
  u16 tmp[8];
#pragma unroll
  for (int i = 0; i < 8; i++) tmp[i] = T[(c0 + i) * 72 + r0];
  *(uint4*)&dst[(size_t)r0 * Sc + c0] = *(uint4*)tmp;
#pragma unroll
  for (int i = 0; i < 8; i++) tmp[i] = T[(c0 + i) * 72 + r0 + 32];
  *(uint4*)&dst[(size_t)(r0 + 32) * Sc + c0] = *(uint4*)tmp;
}

// ---------------- fused attention ----------------
// Max-free two-pass softmax:
//   pass 1: k-col-split across waves, Q frags in regs, per-lane deferred l
//           accumulation (no shuffles in loop), double-buffered K staging
//           with async-split (loads early, ds_write late, 1 barrier/kt).
//   pass 2: q-row-split (as before), a written DIRECTLY from regs as f32,
//           P->LDS kept only for the PV MFMA A-operand.
__global__ __launch_bounds__(256) void attn_kernel(
    const u16* __restrict__ Qp, const u16* __restrict__ Kp, const u16* __restrict__ Vt,
    float* __restrict__ a_out, u16* __restrict__ Oh)
{
  __shared__ __attribute__((aligned(16))) u16 Qs[64 * 72];
  __shared__ __attribute__((aligned(16))) u16 Kb0[64 * 72];
  __shared__ __attribute__((aligned(16))) u16 Kb1[64 * 72];
  __shared__ __attribute__((aligned(16))) u16 Ps[4 * 16 * 72];
  __shared__ float Lb[4][64];

  int tid = threadIdx.x;
  int lane = tid & 63, w = tid >> 6;
  int qd = lane >> 4, ln = lane & 15;
  int qb = blockIdx.x;
  int bh = blockIdx.y;
  int b = bh >> 4, h = bh & 15;

  const u16* Qg = Qp + (size_t)(b * Sc + qb * 64) * Dc + h * 64;
  const u16* Kg = Kp + (size_t)b * Sc * Dc + h * 64;
  const u16* Vg = Vt + (size_t)bh * 64 * Sc;

  int r0 = tid >> 3, c0 = (tid & 7) * 8;

  // load Q tile + first K tile
  *(uint4*)&Qs[r0 * 72 + c0]         = *(const uint4*)&Qg[(size_t)r0 * Dc + c0];
  *(uint4*)&Qs[(r0 + 32) * 72 + c0]  = *(const uint4*)&Qg[(size_t)(r0 + 32) * Dc + c0];
  *(uint4*)&Kb0[r0 * 72 + c0]        = *(const uint4*)&Kg[(size_t)r0 * Dc + c0];
  *(uint4*)&Kb0[(r0 + 32) * 72 + c0] = *(const uint4*)&Kg[(size_t)(r0 + 32) * Dc + c0];
  __syncthreads();

  // hoist all Q fragments (64 rows) into registers
  bf16x8 af0[4], af1[4];
#pragma unroll
  for (int i = 0; i < 4; i++) {
    af0[i] = *(const bf16x8*)&Qs[(i * 16 + ln) * 72 + qd * 8];
    af1[i] = *(const bf16x8*)&Qs[(i * 16 + ln) * 72 + 32 + qd * 8];
  }

  const float cs = 0.125f * 1.44269504088896f;  // 1/sqrt(Dh) * log2(e)
  float l_acc[16];
#pragma unroll
  for (int t = 0; t < 16; t++) l_acc[t] = 0.f;

  // ---- pass 1: per-lane sum of exp2(u); wave w owns tile cols w*16..w*16+15 ----
  for (int kt = 0; kt < 32; ++kt) {
    u16* cur = (kt & 1) ? Kb1 : Kb0;
    u16* nxt = (kt & 1) ? Kb0 : Kb1;
    uint4 ra, rb;
    if (kt < 31) {   // issue next-tile loads early (hide under compute)
      const u16* Kt_ = Kg + (size_t)((kt + 1) * 64) * Dc;
      ra = *(const uint4*)&Kt_[(size_t)r0 * Dc + c0];
      rb = *(const uint4*)&Kt_[(size_t)(r0 + 32) * Dc + c0];
    }
    bf16x8 b0 = *(const bf16x8*)&cur[(w * 16 + ln) * 72 + qd * 8];
    bf16x8 b1 = *(const bf16x8*)&cur[(w * 16 + ln) * 72 + 32 + qd * 8];
#pragma unroll
    for (int i = 0; i < 4; i++) {
      f32x4 s = f32x4{0.f, 0.f, 0.f, 0.f};
      s = MFMA_BF16(af0[i], b0, s);
      s = MFMA_BF16(af1[i], b1, s);
#pragma unroll
      for (int r = 0; r < 4; r++)
        l_acc[i * 4 + r] += exp2f(s[r] * cs);
    }
    if (kt < 31) {
      *(uint4*)&nxt[r0 * 72 + c0]        = ra;
      *(uint4*)&nxt[(r0 + 32) * 72 + c0] = rb;
    }
    __syncthreads();
  }

  // issue pass-2 prologue loads (kt=0 K and V) before the reduction work
  uint4 ka0, ka1, va0, va1;
  {
    ka0 = *(const uint4*)&Kg[(size_t)r0 * Dc + c0];
    ka1 = *(const uint4*)&Kg[(size_t)(r0 + 32) * Dc + c0];
    va0 = *(const uint4*)&Vg[(size_t)r0 * Sc + c0];
    va1 = *(const uint4*)&Vg[(size_t)(r0 + 32) * Sc + c0];
  }

  // reduce l over the 16 ln-lanes (deferred; once per kernel)
#pragma unroll
  for (int t = 0; t < 16; t++) {
    float v = l_acc[t];
    v += __shfl_xor(v, 1);
    v += __shfl_xor(v, 2);
    v += __shfl_xor(v, 4);
    v += __shfl_xor(v, 8);
    l_acc[t] = v;
  }
  if (ln == 0) {
#pragma unroll
    for (int i = 0; i < 4; i++)
#pragma unroll
      for (int r = 0; r < 4; r++)
        Lb[w][i * 16 + qd * 4 + r] = l_acc[i * 4 + r];
  }
  // write kt=0 staged tiles, then one barrier covers both Lb and stage
  *(uint4*)&Kb0[r0 * 72 + c0]        = ka0;
  *(uint4*)&Kb0[(r0 + 32) * 72 + c0] = ka1;
  *(uint4*)&Kb1[r0 * 72 + c0]        = va0;
  *(uint4*)&Kb1[(r0 + 32) * 72 + c0] = va1;
  __syncthreads();

  float inv_l[4];
#pragma unroll
  for (int r = 0; r < 4; r++) {
    int row = w * 16 + qd * 4 + r;
    inv_l[r] = 1.f / (Lb[0][row] + Lb[1][row] + Lb[2][row] + Lb[3][row]);
  }

  bf16x8 qa0 = *(const bf16x8*)&Qs[(w * 16 + ln) * 72 + qd * 8];
  bf16x8 qa1 = *(const bf16x8*)&Qs[(w * 16 + ln) * 72 + 32 + qd * 8];

  f32x4 o[4];
#pragma unroll
  for (int j = 0; j < 4; j++) o[j] = f32x4{0.f, 0.f, 0.f, 0.f};
  float* a_base = a_out + ((size_t)bh * Sc + qb * 64) * Sc;
  u16* Pw = Ps + w * 16 * 72;

  // ---- pass 2: recompute scores, write f32 a from regs, accumulate O = P@V ----
  for (int kt = 0; kt < 32; ++kt) {
    uint4 ra0, ra1, rv0, rv1;
    if (kt < 31) {   // issue next-tile loads early
      const u16* Kt_ = Kg + (size_t)((kt + 1) * 64) * Dc;
      const u16* Vt_ = Vg + (kt + 1) * 64;
      ra0 = *(const uint4*)&Kt_[(size_t)r0 * Dc + c0];
      ra1 = *(const uint4*)&Kt_[(size_t)(r0 + 32) * Dc + c0];
      rv0 = *(const uint4*)&Vt_[(size_t)r0 * Sc + c0];
      rv1 = *(const uint4*)&Vt_[(size_t)(r0 + 32) * Sc + c0];
    }
    f32x4 s[4];
#pragma unroll
    for (int j = 0; j < 4; j++) {
      s[j] = f32x4{0.f, 0.f, 0.f, 0.f};
      bf16x8 b0 = *(const bf16x8*)&Kb0[(j * 16 + ln) * 72 + qd * 8];
      bf16x8 b1 = *(const bf16x8*)&Kb0[(j * 16 + ln) * 72 + 32 + qd * 8];
      s[j] = MFMA_BF16(qa0, b0, s[j]);
      s[j] = MFMA_BF16(qa1, b1, s[j]);
    }
    // normalized P: f32 a-write direct from regs + bf16 copy to LDS for PV
#pragma unroll
    for (int j = 0; j < 4; j++) {
#pragma unroll
      for (int r = 0; r < 4; r++) {
        float p = exp2f(s[j][r] * cs) * inv_l[r];
        a_base[(size_t)(w * 16 + qd * 4 + r) * Sc + kt * 64 + j * 16 + ln] = p;
        Pw[(qd * 4 + r) * 72 + j * 16 + ln] = f32_to_bf16(p);
      }
    }
    // O += P @ V
    bf16x8 pa0 = *(const bf16x8*)&Pw[ln * 72 + qd * 8];
    bf16x8 pa1 = *(const bf16x8*)&Pw[ln * 72 + 32 + qd * 8];
#pragma unroll
    for (int j = 0; j < 4; j++) {
      bf16x8 vb0 = *(const bf16x8*)&Kb1[(j * 16 + ln) * 72 + qd * 8];
      bf16x8 vb1 = *(const bf16x8*)&Kb1[(j * 16 + ln) * 72 + 32 + qd * 8];
      o[j] = MFMA_BF16(pa0, vb0, o[j]);
      o[j] = MFMA_BF16(pa1, vb1, o[j]);
    }
    if (kt < 31) {
      __syncthreads();   // all reads of Kb0/Kb1 this iteration done
      *(uint4*)&Kb0[r0 * 72 + c0]        = ra0;
      *(uint4*)&Kb0[(r0 + 32) * 72 + c0] = ra1;
      *(uint4*)&Kb1[r0 * 72 + c0]        = rv0;
      *(uint4*)&Kb1[(r0 + 32) * 72 + c0] = rv1;
      __syncthreads();   // staged tiles visible
    }
  }

  // write O (bf16) into [B,S,D] head-interleaved layout
  u16* Og = Oh + (size_t)(b * Sc + qb * 64) * Dc + h * 64;
#pragma unroll
  for (int j = 0; j < 4; j++)
#pragma unroll
    for (int r = 0; r < 4; r++)
      Og[(size_t)(w * 16 + qd * 4 + r) * Dc + j * 16 + ln] = f32_to_bf16(o[j][r]);
}

extern "C" void kernel_launch(void* const* d_in, const int* in_sizes, int n_in,
                              void* d_out, int out_size, void* d_ws, size_t ws_size,
                              hipStream_t stream)
{
  const float* q  = (const float*)d_in[0];
  const float* k  = (const float*)d_in[1];
  const float* v  = (const float*)d_in[2];
  const float* Wq = (const float*)d_in[3];
  const float* bq = (const float*)d_in[4];
  const float* Wk = (const float*)d_in[5];
  const float* bk = (const float*)d_in[6];
  const float* Wv = (const float*)d_in[7];
  const float* bv = (const float*)d_in[8];
  const float* Wo = (const float*)d_in[9];
  const float* bo = (const float*)d_in[10];

  u16* ws = (u16*)d_ws;
  u16* qb  = ws + OFF_QB;
  u16* kb  = ws + OFF_KB;
  u16* vb  = ws + OFF_VB;
  u16* Wqb = ws + OFF_WQB;
  u16* Wkb = ws + OFF_WKB;
  u16* Wvb = ws + OFF_WVB;
  u16* Wob = ws + OFF_WOB;
  u16* Qp  = ws + OFF_QP;
  u16* Kp  = ws + OFF_KP;
  u16* Vp  = ws + OFF_VP;
  u16* Vt  = ws + OFF_VT;
  u16* Oh  = ws + OFF_OH;

  float* out_o = (float*)d_out;                 // [2,2048,1024]
  float* out_a = out_o + 4194304;               // [2,16,2048,2048]

  cvt_all<<<dim3(2048, 7), 256, 0, stream>>>(q, k, v, Wq, Wk, Wv, Wo, ws);
  qkv_gemm<<<dim3(8, 32, 3), 256, 0, stream>>>(qb, kb, vb, Wqb, Wkb, Wvb, bq, bk, bv, Qp, Kp, Vp);
  transpose_v<<<dim3(32, 32), 256, 0, stream>>>(Vp, Vt);
  attn_kernel<<<dim3(32, 32), 256, 0, stream>>>(Qp, Kp, Vt, out_a, Oh);
  out_gemm<<<dim3(8, 32), 256, 0, stream>>>(Oh, Wob, bo, out_o);
}

// Round 2
// 790.789 us; speedup vs baseline: 1.0685x; 1.0035x over previous
//
#include <hip/hip_runtime.h>

typedef unsigned short u16;
typedef __bf16 bf16x8 __attribute__((ext_vector_type(8)));
typedef float f32x4 __attribute__((ext_vector_type(4)));

#define MFMA_BF16(a,b,c) __builtin_amdgcn_mfma_f32_16x16x32_bf16((a),(b),(c),0,0,0)

// ---- constants ----
#define Bc 2
#define Sc 2048
#define Dc 1024
#define Hc 16
#define Dh 64
#define Mrows (Bc*Sc)          // 4096

// ws element offsets (u16 units)
#define OFF_QB   0u
#define OFF_KB   4194304u
#define OFF_VB   8388608u
#define OFF_WQB  12582912u
#define OFF_WKB  13631488u
#define OFF_WVB  14680064u
#define OFF_WOB  15728640u
#define OFF_QP   16777216u
#define OFF_KP   20971520u
#define OFF_VP   25165824u
#define OFF_VT   29360128u
#define OFF_OH   33554432u
// total = 37748736 u16 = 75,497,472 bytes of ws

__device__ __forceinline__ u16 f32_to_bf16(float f) {
  unsigned u = __builtin_bit_cast(unsigned, f);
  u += 0x7FFFu + ((u >> 16) & 1u);
  return (u16)(u >> 16);
}
__device__ __forceinline__ float bf16_to_f32(u16 x) {
  return __builtin_bit_cast(float, ((unsigned)x) << 16);
}

// async global->LDS, 16B per lane: LDS dest = wave-uniform base + lane*16B
__device__ __forceinline__ void gload16(const u16* g, u16* l) {
  __builtin_amdgcn_global_load_lds(
      (__attribute__((address_space(1))) void*)(g),
      (__attribute__((address_space(3))) void*)(l),
      16, 0, 0);
}

// ---------------- fp32 -> bf16 conversion of all inputs ----------------
__global__ __launch_bounds__(256) void cvt_all(
    const float* __restrict__ q, const float* __restrict__ k, const float* __restrict__ v,
    const float* __restrict__ wq, const float* __restrict__ wk,
    const float* __restrict__ wv, const float* __restrict__ wo,
    u16* __restrict__ ws)
{
  int y = blockIdx.y;
  const float* src; u16* dst; int n;
  if (y < 3) {
    src = (y == 0) ? q : (y == 1) ? k : v;
    dst = ws + (unsigned)y * 4194304u;
    n = 4194304;
  } else {
    src = (y == 3) ? wq : (y == 4) ? wk : (y == 5) ? wv : wo;
    dst = ws + OFF_WQB + (unsigned)(y - 3) * 1048576u;
    n = 1048576;
  }
  int i = (blockIdx.x * 256 + threadIdx.x) * 8;
  if (i >= n) return;
  float4 f0 = *(const float4*)(src + i);
  float4 f1 = *(const float4*)(src + i + 4);
  u16 o[8];
  o[0] = f32_to_bf16(f0.x); o[1] = f32_to_bf16(f0.y);
  o[2] = f32_to_bf16(f0.z); o[3] = f32_to_bf16(f0.w);
  o[4] = f32_to_bf16(f1.x); o[5] = f32_to_bf16(f1.y);
  o[6] = f32_to_bf16(f1.z); o[7] = f32_to_bf16(f1.w);
  *(uint4*)(dst + i) = *(uint4*)o;
}

// ---------------- 128x128 NT GEMM body (C = X @ W^T + bias) ----------------
// m97-structure: linear LDS tiles [128][32] (64B rows), global_load_lds
// width-16 staging (4 per wave per k-step), 2-barrier loop.
__device__ __forceinline__ void gemm128_body(
    const u16* __restrict__ X, const u16* __restrict__ W, const float* __restrict__ bias,
    u16* __restrict__ out_bf, float* __restrict__ out_f,
    u16* As, u16* Bs, int m0, int n0)
{
  int tid = threadIdx.x;
  int lane = tid & 63, w = tid >> 6;
  int wr = w >> 1, wc = w & 1;
  int qd = lane >> 4, ln = lane & 15;

  f32x4 acc[4][4];
#pragma unroll
  for (int i = 0; i < 4; i++)
#pragma unroll
    for (int j = 0; j < 4; j++) acc[i][j] = f32x4{0.f, 0.f, 0.f, 0.f};

  // staging: wave w's first gload covers tile rows [w*16, w*16+16),
  // second covers [w*16+64, w*16+80). lane l -> row +l/4, col (l&3)*8 u16.
  int srow = w * 16 + (lane >> 2);
  int scol = (lane & 3) * 8;
  const u16* Xa = X + (size_t)(m0 + srow) * 1024 + scol;
  const u16* Xb = Xa + (size_t)64 * 1024;
  const u16* Wa = W + (size_t)(n0 + srow) * 1024 + scol;
  const u16* Wb = Wa + (size_t)64 * 1024;
  u16* asA0 = As + (w * 16) * 32;        // wave-uniform LDS bases
  u16* asA1 = As + (w * 16 + 64) * 32;
  u16* asB0 = Bs + (w * 16) * 32;
  u16* asB1 = Bs + (w * 16 + 64) * 32;

  for (int k0 = 0; k0 < 1024; k0 += 32) {
    __syncthreads();                      // prior iter's ds_reads done
    gload16(Xa + k0, asA0);
    gload16(Xb + k0, asA1);
    gload16(Wa + k0, asB0);
    gload16(Wb + k0, asB1);
    __syncthreads();                      // vmcnt(0) drain + barrier
    bf16x8 af[4], bfr[4];
#pragma unroll
    for (int i = 0; i < 4; i++)
      af[i] = *(const bf16x8*)&As[(wr * 64 + i * 16 + ln) * 32 + qd * 8];
#pragma unroll
    for (int j = 0; j < 4; j++)
      bfr[j] = *(const bf16x8*)&Bs[(wc * 64 + j * 16 + ln) * 32 + qd * 8];
#pragma unroll
    for (int i = 0; i < 4; i++)
#pragma unroll
      for (int j = 0; j < 4; j++)
        acc[i][j] = MFMA_BF16(af[i], bfr[j], acc[i][j]);
  }

#pragma unroll
  for (int i = 0; i < 4; i++) {
#pragma unroll
    for (int j = 0; j < 4; j++) {
      int col = n0 + wc * 64 + j * 16 + ln;
      float bv = bias[col];
#pragma unroll
      for (int r = 0; r < 4; r++) {
        int row = m0 + wr * 64 + i * 16 + qd * 4 + r;
        float val = acc[i][j][r] + bv;
        if (out_bf) out_bf[(size_t)row * 1024 + col] = f32_to_bf16(val);
        else        out_f[(size_t)row * 1024 + col]  = val;
      }
    }
  }
}

__global__ __launch_bounds__(256) void qkv_gemm(
    const u16* __restrict__ xq, const u16* __restrict__ xk, const u16* __restrict__ xv,
    const u16* __restrict__ wq, const u16* __restrict__ wk, const u16* __restrict__ wv,
    const float* __restrict__ bq, const float* __restrict__ bk, const float* __restrict__ bv,
    u16* __restrict__ Qp, u16* __restrict__ Kp, u16* __restrict__ Vp)
{
  __shared__ __attribute__((aligned(16))) u16 As[128 * 32];
  __shared__ __attribute__((aligned(16))) u16 Bs[128 * 32];
  const u16 *X, *W; const float* bias; u16* out;
  int z = blockIdx.z;
  if (z == 0)      { X = xq; W = wq; bias = bq; out = Qp; }
  else if (z == 1) { X = xk; W = wk; bias = bk; out = Kp; }
  else             { X = xv; W = wv; bias = bv; out = Vp; }
  gemm128_body(X, W, bias, out, nullptr, As, Bs, blockIdx.y * 128, blockIdx.x * 128);
}

__global__ __launch_bounds__(256) void out_gemm(
    const u16* __restrict__ Oh, const u16* __restrict__ Wo, const float* __restrict__ bo,
    float* __restrict__ out)
{
  __shared__ __attribute__((aligned(16))) u16 As[128 * 32];
  __shared__ __attribute__((aligned(16))) u16 Bs[128 * 32];
  gemm128_body(Oh, Wo, bo, nullptr, out, As, Bs, blockIdx.y * 128, blockIdx.x * 128);
}

// ---------------- V transpose: Vp [B,S,D] -> Vt [B*H, Dh, S] ----------------
__global__ __launch_bounds__(256) void transpose_v(const u16* __restrict__ Vp, u16* __restrict__ Vt)
{
  __shared__ __attribute__((aligned(16))) u16 T[64 * 72];
  int tid = threadIdx.x;
  int st = blockIdx.x;    // s tile 0..31
  int bh = blockIdx.y;    // 0..31
  int b = bh >> 4, h = bh & 15;
  int r0 = tid >> 3, c0 = (tid & 7) * 8;
  const u16* src = Vp + (size_t)(b * Sc + st * 64) * Dc + h * 64;
  *(uint4*)&T[r0 * 72 + c0]        = *(const uint4*)&src[(size_t)r0 * Dc + c0];
  *(uint4*)&T[(r0 + 32) * 72 + c0] = *(const uint4*)&src[(size_t)(r0 + 32) * Dc + c0];
  __syncthreads();
  u16* dst = Vt + (size_t)bh * 64 * Sc + st * 64;
  u16 tmp[8];
#pragma unroll
  for (int i = 0; i < 8; i++) tmp[i] = T[(c0 + i) * 72 + r0];
  *(uint4*)&dst[(size_t)r0 * Sc + c0] = *(uint4*)tmp;
#pragma unroll
  for (int i = 0; i < 8; i++) tmp[i] = T[(c0 + i) * 72 + r0 + 32];
  *(uint4*)&dst[(size_t)(r0 + 32) * Sc + c0] = *(uint4*)tmp;
}

// ---------------- fused attention ----------------
// Max-free two-pass softmax (unchanged from round 1):
//   pass 1: k-col-split across waves, Q frags in regs, per-lane deferred l
//           accumulation, double-buffered K staging, 1 barrier/kt.
//   pass 2: q-row-split, a written directly from regs as f32,
//           P->LDS kept only for the PV MFMA A-operand.
__global__ __launch_bounds__(256) void attn_kernel(
    const u16* __restrict__ Qp, const u16* __restrict__ Kp, const u16* __restrict__ Vt,
    float* __restrict__ a_out, u16* __restrict__ Oh)
{
  __shared__ __attribute__((aligned(16))) u16 Qs[64 * 72];
  __shared__ __attribute__((aligned(16))) u16 Kb0[64 * 72];
  __shared__ __attribute__((aligned(16))) u16 Kb1[64 * 72];
  __shared__ __attribute__((aligned(16))) u16 Ps[4 * 16 * 72];
  __shared__ float Lb[4][64];

  int tid = threadIdx.x;
  int lane = tid & 63, w = tid >> 6;
  int qd = lane >> 4, ln = lane & 15;
  int qb = blockIdx.x;
  int bh = blockIdx.y;
  int b = bh >> 4, h = bh & 15;

  const u16* Qg = Qp + (size_t)(b * Sc + qb * 64) * Dc + h * 64;
  const u16* Kg = Kp + (size_t)b * Sc * Dc + h * 64;
  const u16* Vg = Vt + (size_t)bh * 64 * Sc;

  int r0 = tid >> 3, c0 = (tid & 7) * 8;

  // load Q tile + first K tile
  *(uint4*)&Qs[r0 * 72 + c0]         = *(const uint4*)&Qg[(size_t)r0 * Dc + c0];
  *(uint4*)&Qs[(r0 + 32) * 72 + c0]  = *(const uint4*)&Qg[(size_t)(r0 + 32) * Dc + c0];
  *(uint4*)&Kb0[r0 * 72 + c0]        = *(const uint4*)&Kg[(size_t)r0 * Dc + c0];
  *(uint4*)&Kb0[(r0 + 32) * 72 + c0] = *(const uint4*)&Kg[(size_t)(r0 + 32) * Dc + c0];
  __syncthreads();

  // hoist all Q fragments (64 rows) into registers
  bf16x8 af0[4], af1[4];
#pragma unroll
  for (int i = 0; i < 4; i++) {
    af0[i] = *(const bf16x8*)&Qs[(i * 16 + ln) * 72 + qd * 8];
    af1[i] = *(const bf16x8*)&Qs[(i * 16 + ln) * 72 + 32 + qd * 8];
  }

  const float cs = 0.125f * 1.44269504088896f;  // 1/sqrt(Dh) * log2(e)
  float l_acc[16];
#pragma unroll
  for (int t = 0; t < 16; t++) l_acc[t] = 0.f;

  // ---- pass 1: per-lane sum of exp2(u); wave w owns tile cols w*16..w*16+15 ----
  for (int kt = 0; kt < 32; ++kt) {
    u16* cur = (kt & 1) ? Kb1 : Kb0;
    u16* nxt = (kt & 1) ? Kb0 : Kb1;
    uint4 ra, rb;
    if (kt < 31) {   // issue next-tile loads early (hide under compute)
      const u16* Kt_ = Kg + (size_t)((kt + 1) * 64) * Dc;
      ra = *(const uint4*)&Kt_[(size_t)r0 * Dc + c0];
      rb = *(const uint4*)&Kt_[(size_t)(r0 + 32) * Dc + c0];
    }
    bf16x8 b0 = *(const bf16x8*)&cur[(w * 16 + ln) * 72 + qd * 8];
    bf16x8 b1 = *(const bf16x8*)&cur[(w * 16 + ln) * 72 + 32 + qd * 8];
#pragma unroll
    for (int i = 0; i < 4; i++) {
      f32x4 s = f32x4{0.f, 0.f, 0.f, 0.f};
      s = MFMA_BF16(af0[i], b0, s);
      s = MFMA_BF16(af1[i], b1, s);
#pragma unroll
      for (int r = 0; r < 4; r++)
        l_acc[i * 4 + r] += exp2f(s[r] * cs);
    }
    if (kt < 31) {
      *(uint4*)&nxt[r0 * 72 + c0]        = ra;
      *(uint4*)&nxt[(r0 + 32) * 72 + c0] = rb;
    }
    __syncthreads();
  }

  // issue pass-2 prologue loads (kt=0 K and V) before the reduction work
  uint4 ka0, ka1, va0, va1;
  {
    ka0 = *(const uint4*)&Kg[(size_t)r0 * Dc + c0];
    ka1 = *(const uint4*)&Kg[(size_t)(r0 + 32) * Dc + c0];
    va0 = *(const uint4*)&Vg[(size_t)r0 * Sc + c0];
    va1 = *(const uint4*)&Vg[(size_t)(r0 + 32) * Sc + c0];
  }

  // reduce l over the 16 ln-lanes (deferred; once per kernel)
#pragma unroll
  for (int t = 0; t < 16; t++) {
    float v = l_acc[t];
    v += __shfl_xor(v, 1);
    v += __shfl_xor(v, 2);
    v += __shfl_xor(v, 4);
    v += __shfl_xor(v, 8);
    l_acc[t] = v;
  }
  if (ln == 0) {
#pragma unroll
    for (int i = 0; i < 4; i++)
#pragma unroll
      for (int r = 0; r < 4; r++)
        Lb[w][i * 16 + qd * 4 + r] = l_acc[i * 4 + r];
  }
  // write kt=0 staged tiles, then one barrier covers both Lb and stage
  *(uint4*)&Kb0[r0 * 72 + c0]        = ka0;
  *(uint4*)&Kb0[(r0 + 32) * 72 + c0] = ka1;
  *(uint4*)&Kb1[r0 * 72 + c0]        = va0;
  *(uint4*)&Kb1[(r0 + 32) * 72 + c0] = va1;
  __syncthreads();

  float inv_l[4];
#pragma unroll
  for (int r = 0; r < 4; r++) {
    int row = w * 16 + qd * 4 + r;
    inv_l[r] = 1.f / (Lb[0][row] + Lb[1][row] + Lb[2][row] + Lb[3][row]);
  }

  bf16x8 qa0 = *(const bf16x8*)&Qs[(w * 16 + ln) * 72 + qd * 8];
  bf16x8 qa1 = *(const bf16x8*)&Qs[(w * 16 + ln) * 72 + 32 + qd * 8];

  f32x4 o[4];
#pragma unroll
  for (int j = 0; j < 4; j++) o[j] = f32x4{0.f, 0.f, 0.f, 0.f};
  float* a_base = a_out + ((size_t)bh * Sc + qb * 64) * Sc;
  u16* Pw = Ps + w * 16 * 72;

  // ---- pass 2: recompute scores, write f32 a from regs, accumulate O = P@V ----
  for (int kt = 0; kt < 32; ++kt) {
    uint4 ra0, ra1, rv0, rv1;
    if (kt < 31) {   // issue next-tile loads early
      const u16* Kt_ = Kg + (size_t)((kt + 1) * 64) * Dc;
      const u16* Vt_ = Vg + (kt + 1) * 64;
      ra0 = *(const uint4*)&Kt_[(size_t)r0 * Dc + c0];
      ra1 = *(const uint4*)&Kt_[(size_t)(r0 + 32) * Dc + c0];
      rv0 = *(const uint4*)&Vt_[(size_t)r0 * Sc + c0];
      rv1 = *(const uint4*)&Vt_[(size_t)(r0 + 32) * Sc + c0];
    }
    f32x4 s[4];
#pragma unroll
    for (int j = 0; j < 4; j++) {
      s[j] = f32x4{0.f, 0.f, 0.f, 0.f};
      bf16x8 b0 = *(const bf16x8*)&Kb0[(j * 16 + ln) * 72 + qd * 8];
      bf16x8 b1 = *(const bf16x8*)&Kb0[(j * 16 + ln) * 72 + 32 + qd * 8];
      s[j] = MFMA_BF16(qa0, b0, s[j]);
      s[j] = MFMA_BF16(qa1, b1, s[j]);
    }
    // normalized P: f32 a-write direct from regs + bf16 copy to LDS for PV
#pragma unroll
    for (int j = 0; j < 4; j++) {
#pragma unroll
      for (int r = 0; r < 4; r++) {
        float p = exp2f(s[j][r] * cs) * inv_l[r];
        a_base[(size_t)(w * 16 + qd * 4 + r) * Sc + kt * 64 + j * 16 + ln] = p;
        Pw[(qd * 4 + r) * 72 + j * 16 + ln] = f32_to_bf16(p);
      }
    }
    // O += P @ V
    bf16x8 pa0 = *(const bf16x8*)&Pw[ln * 72 + qd * 8];
    bf16x8 pa1 = *(const bf16x8*)&Pw[ln * 72 + 32 + qd * 8];
#pragma unroll
    for (int j = 0; j < 4; j++) {
      bf16x8 vb0 = *(const bf16x8*)&Kb1[(j * 16 + ln) * 72 + qd * 8];
      bf16x8 vb1 = *(const bf16x8*)&Kb1[(j * 16 + ln) * 72 + 32 + qd * 8];
      o[j] = MFMA_BF16(pa0, vb0, o[j]);
      o[j] = MFMA_BF16(pa1, vb1, o[j]);
    }
    if (kt < 31) {
      __syncthreads();   // all reads of Kb0/Kb1 this iteration done
      *(uint4*)&Kb0[r0 * 72 + c0]        = ra0;
      *(uint4*)&Kb0[(r0 + 32) * 72 + c0] = ra1;
      *(uint4*)&Kb1[r0 * 72 + c0]        = rv0;
      *(uint4*)&Kb1[(r0 + 32) * 72 + c0] = rv1;
      __syncthreads();   // staged tiles visible
    }
  }

  // write O (bf16) into [B,S,D] head-interleaved layout
  u16* Og = Oh + (size_t)(b * Sc + qb * 64) * Dc + h * 64;
#pragma unroll
  for (int j = 0; j < 4; j++)
#pragma unroll
    for (int r = 0; r < 4; r++)
      Og[(size_t)(w * 16 + qd * 4 + r) * Dc + j * 16 + ln] = f32_to_bf16(o[j][r]);
}

extern "C" void kernel_launch(void* const* d_in, const int* in_sizes, int n_in,
                              void* d_out, int out_size, void* d_ws, size_t ws_size,
                              hipStream_t stream)
{
  const float* q  = (const float*)d_in[0];
  const float* k  = (const float*)d_in[1];
  const float* v  = (const float*)d_in[2];
  const float* Wq = (const float*)d_in[3];
  const float* bq = (const float*)d_in[4];
  const float* Wk = (const float*)d_in[5];
  const float* bk = (const float*)d_in[6];
  const float* Wv = (const float*)d_in[7];
  const float* bv = (const float*)d_in[8];
  const float* Wo = (const float*)d_in[9];
  const float* bo = (const float*)d_in[10];

  u16* ws = (u16*)d_ws;
  u16* qb  = ws + OFF_QB;
  u16* kb  = ws + OFF_KB;
  u16* vb  = ws + OFF_VB;
  u16* Wqb = ws + OFF_WQB;
  u16* Wkb = ws + OFF_WKB;
  u16* Wvb = ws + OFF_WVB;
  u16* Wob = ws + OFF_WOB;
  u16* Qp  = ws + OFF_QP;
  u16* Kp  = ws + OFF_KP;
  u16* Vp  = ws + OFF_VP;
  u16* Vt  = ws + OFF_VT;
  u16* Oh  = ws + OFF_OH;

  float* out_o = (float*)d_out;                 // [2,2048,1024]
  float* out_a = out_o + 4194304;               // [2,16,2048,2048]

  cvt_all<<<dim3(2048, 7), 256, 0, stream>>>(q, k, v, Wq, Wk, Wv, Wo, ws);
  qkv_gemm<<<dim3(8, 32, 3), 256, 0, stream>>>(qb, kb, vb, Wqb, Wkb, Wvb, bq, bk, bv, Qp, Kp, Vp);
  transpose_v<<<dim3(32, 32), 256, 0, stream>>>(Vp, Vt);
  attn_kernel<<<dim3(32, 32), 256, 0, stream>>>(Qp, Kp, Vt, out_a, Oh);
  out_gemm<<<dim3(8, 32), 256, 0, stream>>>(Oh, Wob, bo, out_o);
}

// Round 3
// 765.123 us; speedup vs baseline: 1.1044x; 1.0335x over previous
//
#include <hip/hip_runtime.h>

typedef unsigned short u16;
typedef __bf16 bf16x8 __attribute__((ext_vector_type(8)));
typedef float f32x4 __attribute__((ext_vector_type(4)));

#define MFMA_BF16(a,b,c) __builtin_amdgcn_mfma_f32_16x16x32_bf16((a),(b),(c),0,0,0)

// ---- constants ----
#define Bc 2
#define Sc 2048
#define Dc 1024
#define Hc 16
#define Dh 64
#define Mrows (Bc*Sc)          // 4096

// ws element offsets (u16 units)
#define OFF_QB   0u
#define OFF_KB   4194304u
#define OFF_VB   8388608u
#define OFF_WQB  12582912u
#define OFF_WKB  13631488u
#define OFF_WVB  14680064u
#define OFF_WOB  15728640u
#define OFF_QP   16777216u
#define OFF_KP   20971520u
#define OFF_VP   25165824u
#define OFF_VT   29360128u
#define OFF_OH   33554432u
// total = 37748736 u16 = 75,497,472 bytes of ws

__device__ __forceinline__ u16 f32_to_bf16(float f) {
  unsigned u = __builtin_bit_cast(unsigned, f);
  u += 0x7FFFu + ((u >> 16) & 1u);
  return (u16)(u >> 16);
}
__device__ __forceinline__ float bf16_to_f32(u16 x) {
  return __builtin_bit_cast(float, ((unsigned)x) << 16);
}

// async global->LDS, 16B per lane: LDS dest = wave-uniform base + lane*16B
__device__ __forceinline__ void gload16(const u16* g, u16* l) {
  __builtin_amdgcn_global_load_lds(
      (__attribute__((address_space(1))) void*)(g),
      (__attribute__((address_space(3))) void*)(l),
      16, 0, 0);
}

// ---------------- fp32 -> bf16 conversion of all inputs ----------------
__global__ __launch_bounds__(256) void cvt_all(
    const float* __restrict__ q, const float* __restrict__ k, const float* __restrict__ v,
    const float* __restrict__ wq, const float* __restrict__ wk,
    const float* __restrict__ wv, const float* __restrict__ wo,
    u16* __restrict__ ws)
{
  int y = blockIdx.y;
  const float* src; u16* dst; int n;
  if (y < 3) {
    src = (y == 0) ? q : (y == 1) ? k : v;
    dst = ws + (unsigned)y * 4194304u;
    n = 4194304;
  } else {
    src = (y == 3) ? wq : (y == 4) ? wk : (y == 5) ? wv : wo;
    dst = ws + OFF_WQB + (unsigned)(y - 3) * 1048576u;
    n = 1048576;
  }
  int i = (blockIdx.x * 256 + threadIdx.x) * 8;
  if (i >= n) return;
  float4 f0 = *(const float4*)(src + i);
  float4 f1 = *(const float4*)(src + i + 4);
  u16 o[8];
  o[0] = f32_to_bf16(f0.x); o[1] = f32_to_bf16(f0.y);
  o[2] = f32_to_bf16(f0.z); o[3] = f32_to_bf16(f0.w);
  o[4] = f32_to_bf16(f1.x); o[5] = f32_to_bf16(f1.y);
  o[6] = f32_to_bf16(f1.z); o[7] = f32_to_bf16(f1.w);
  *(uint4*)(dst + i) = *(uint4*)o;
}

// ---------------- 128x128 NT GEMM body (C = X @ W^T + bias) ----------------
// m97-structure: linear LDS tiles [128][32] (64B rows), global_load_lds
// width-16 staging (4 per wave per k-step), 2-barrier loop.
__device__ __forceinline__ void gemm128_body(
    const u16* __restrict__ X, const u16* __restrict__ W, const float* __restrict__ bias,
    u16* __restrict__ out_bf, float* __restrict__ out_f,
    u16* As, u16* Bs, int m0, int n0)
{
  int tid = threadIdx.x;
  int lane = tid & 63, w = tid >> 6;
  int wr = w >> 1, wc = w & 1;
  int qd = lane >> 4, ln = lane & 15;

  f32x4 acc[4][4];
#pragma unroll
  for (int i = 0; i < 4; i++)
#pragma unroll
    for (int j = 0; j < 4; j++) acc[i][j] = f32x4{0.f, 0.f, 0.f, 0.f};

  int srow = w * 16 + (lane >> 2);
  int scol = (lane & 3) * 8;
  const u16* Xa = X + (size_t)(m0 + srow) * 1024 + scol;
  const u16* Xb = Xa + (size_t)64 * 1024;
  const u16* Wa = W + (size_t)(n0 + srow) * 1024 + scol;
  const u16* Wb = Wa + (size_t)64 * 1024;
  u16* asA0 = As + (w * 16) * 32;        // wave-uniform LDS bases
  u16* asA1 = As + (w * 16 + 64) * 32;
  u16* asB0 = Bs + (w * 16) * 32;
  u16* asB1 = Bs + (w * 16 + 64) * 32;

  for (int k0 = 0; k0 < 1024; k0 += 32) {
    __syncthreads();                      // prior iter's ds_reads done
    gload16(Xa + k0, asA0);
    gload16(Xb + k0, asA1);
    gload16(Wa + k0, asB0);
    gload16(Wb + k0, asB1);
    __syncthreads();                      // vmcnt(0) drain + barrier
    bf16x8 af[4], bfr[4];
#pragma unroll
    for (int i = 0; i < 4; i++)
      af[i] = *(const bf16x8*)&As[(wr * 64 + i * 16 + ln) * 32 + qd * 8];
#pragma unroll
    for (int j = 0; j < 4; j++)
      bfr[j] = *(const bf16x8*)&Bs[(wc * 64 + j * 16 + ln) * 32 + qd * 8];
#pragma unroll
    for (int i = 0; i < 4; i++)
#pragma unroll
      for (int j = 0; j < 4; j++)
        acc[i][j] = MFMA_BF16(af[i], bfr[j], acc[i][j]);
  }

#pragma unroll
  for (int i = 0; i < 4; i++) {
#pragma unroll
    for (int j = 0; j < 4; j++) {
      int col = n0 + wc * 64 + j * 16 + ln;
      float bv = bias[col];
#pragma unroll
      for (int r = 0; r < 4; r++) {
        int row = m0 + wr * 64 + i * 16 + qd * 4 + r;
        float val = acc[i][j][r] + bv;
        if (out_bf) out_bf[(size_t)row * 1024 + col] = f32_to_bf16(val);
        else        out_f[(size_t)row * 1024 + col]  = val;
      }
    }
  }
}

__global__ __launch_bounds__(256) void qkv_gemm(
    const u16* __restrict__ xq, const u16* __restrict__ xk, const u16* __restrict__ xv,
    const u16* __restrict__ wq, const u16* __restrict__ wk, const u16* __restrict__ wv,
    const float* __restrict__ bq, const float* __restrict__ bk, const float* __restrict__ bv,
    u16* __restrict__ Qp, u16* __restrict__ Kp, u16* __restrict__ Vp)
{
  __shared__ __attribute__((aligned(16))) u16 As[128 * 32];
  __shared__ __attribute__((aligned(16))) u16 Bs[128 * 32];
  const u16 *X, *W; const float* bias; u16* out;
  int z = blockIdx.z;
  if (z == 0)      { X = xq; W = wq; bias = bq; out = Qp; }
  else if (z == 1) { X = xk; W = wk; bias = bk; out = Kp; }
  else             { X = xv; W = wv; bias = bv; out = Vp; }
  gemm128_body(X, W, bias, out, nullptr, As, Bs, blockIdx.y * 128, blockIdx.x * 128);
}

__global__ __launch_bounds__(256) void out_gemm(
    const u16* __restrict__ Oh, const u16* __restrict__ Wo, const float* __restrict__ bo,
    float* __restrict__ out)
{
  __shared__ __attribute__((aligned(16))) u16 As[128 * 32];
  __shared__ __attribute__((aligned(16))) u16 Bs[128 * 32];
  gemm128_body(Oh, Wo, bo, nullptr, out, As, Bs, blockIdx.y * 128, blockIdx.x * 128);
}

// ---------------- V transpose: Vp [B,S,D] -> Vt [B*H, Dh, S] ----------------
__global__ __launch_bounds__(256) void transpose_v(const u16* __restrict__ Vp, u16* __restrict__ Vt)
{
  __shared__ __attribute__((aligned(16))) u16 T[64 * 72];
  int tid = threadIdx.x;
  int st = blockIdx.x;    // s tile 0..31
  int bh = blockIdx.y;    // 0..31
  int b = bh >> 4, h = bh & 15;
  int r0 = tid >> 3, c0 = (tid & 7) * 8;
  const u16* src = Vp + (size_t)(b * Sc + st * 64) * Dc + h * 64;
  *(uint4*)&T[r0 * 72 + c0]        = *(const uint4*)&src[(size_t)r0 * Dc + c0];
  *(uint4*)&T[(r0 + 32) * 72 + c0] = *(const uint4*)&src[(size_t)(r0 + 32) * Dc + c0];
  __syncthreads();
  u16* dst = Vt + (size_t)bh * 64 * Sc + st * 64;
  u16 tmp[8];
#pragma unroll
  for (int i = 0; i < 8; i++) tmp[i] = T[(c0 + i) * 72 + r0];
  *(uint4*)&dst[(size_t)r0 * Sc + c0] = *(uint4*)tmp;
#pragma unroll
  for (int i = 0; i < 8; i++) tmp[i] = T[(c0 + i) * 72 + r0 + 32];
  *(uint4*)&dst[(size_t)(r0 + 32) * Sc + c0] = *(uint4*)tmp;
}

// ---------------- fused attention ----------------
// Max-free two-pass softmax.
//   pass 1: k-col-split across waves, Q frags in regs, per-lane deferred l,
//           double-buffered K staging, 1 barrier/kt.
//   pass 2: q-row-split, K AND V double-buffered (V buf 0 reuses the dead Q
//           tile) -> 1 barrier/kt; a written as packed float4 from the
//           per-wave bf16 P tile.
#define BUFW (64 * 72)   // one 64x72 u16 tile (9216 B)

__global__ __launch_bounds__(256) void attn_kernel(
    const u16* __restrict__ Qp, const u16* __restrict__ Kp, const u16* __restrict__ Vt,
    float* __restrict__ a_out, u16* __restrict__ Oh)
{
  // pool: buf0 = Q tile (later V ping), buf1 = K ping, buf2 = K pong,
  //       buf3 = V pong, then Ps (per-wave P tiles)
  __shared__ __attribute__((aligned(16))) u16 pool[5 * BUFW];
  __shared__ float Lb[4][64];
  u16* buf0 = pool;
  u16* buf1 = pool + BUFW;
  u16* buf2 = pool + 2 * BUFW;
  u16* buf3 = pool + 3 * BUFW;
  u16* Ps   = pool + 4 * BUFW;

  int tid = threadIdx.x;
  int lane = tid & 63, w = tid >> 6;
  int qd = lane >> 4, ln = lane & 15;
  int qb = blockIdx.x;
  int bh = blockIdx.y;
  int b = bh >> 4, h = bh & 15;

  const u16* Qg = Qp + (size_t)(b * Sc + qb * 64) * Dc + h * 64;
  const u16* Kg = Kp + (size_t)b * Sc * Dc + h * 64;
  const u16* Vg = Vt + (size_t)bh * 64 * Sc;

  int r0 = tid >> 3, c0 = (tid & 7) * 8;

  // load Q tile + first K tile
  *(uint4*)&buf0[r0 * 72 + c0]        = *(const uint4*)&Qg[(size_t)r0 * Dc + c0];
  *(uint4*)&buf0[(r0 + 32) * 72 + c0] = *(const uint4*)&Qg[(size_t)(r0 + 32) * Dc + c0];
  *(uint4*)&buf1[r0 * 72 + c0]        = *(const uint4*)&Kg[(size_t)r0 * Dc + c0];
  *(uint4*)&buf1[(r0 + 32) * 72 + c0] = *(const uint4*)&Kg[(size_t)(r0 + 32) * Dc + c0];
  __syncthreads();

  // hoist ALL Q fragments (pass 1 and pass 2) into registers; buf0 is then dead
  bf16x8 af0[4], af1[4];
#pragma unroll
  for (int i = 0; i < 4; i++) {
    af0[i] = *(const bf16x8*)&buf0[(i * 16 + ln) * 72 + qd * 8];
    af1[i] = *(const bf16x8*)&buf0[(i * 16 + ln) * 72 + 32 + qd * 8];
  }
  bf16x8 qa0 = *(const bf16x8*)&buf0[(w * 16 + ln) * 72 + qd * 8];
  bf16x8 qa1 = *(const bf16x8*)&buf0[(w * 16 + ln) * 72 + 32 + qd * 8];

  const float cs = 0.125f * 1.44269504088896f;  // 1/sqrt(Dh) * log2(e)
  float l_acc[16];
#pragma unroll
  for (int t = 0; t < 16; t++) l_acc[t] = 0.f;

  // ---- pass 1: per-lane sum of exp2(u); wave w owns tile cols w*16..w*16+15 ----
  for (int kt = 0; kt < 32; ++kt) {
    u16* cur = (kt & 1) ? buf2 : buf1;
    u16* nxt = (kt & 1) ? buf1 : buf2;
    uint4 ra, rb;
    if (kt < 31) {   // issue next-tile loads early (hide under compute)
      const u16* Kt_ = Kg + (size_t)((kt + 1) * 64) * Dc;
      ra = *(const uint4*)&Kt_[(size_t)r0 * Dc + c0];
      rb = *(const uint4*)&Kt_[(size_t)(r0 + 32) * Dc + c0];
    }
    bf16x8 b0 = *(const bf16x8*)&cur[(w * 16 + ln) * 72 + qd * 8];
    bf16x8 b1 = *(const bf16x8*)&cur[(w * 16 + ln) * 72 + 32 + qd * 8];
#pragma unroll
    for (int i = 0; i < 4; i++) {
      f32x4 s = f32x4{0.f, 0.f, 0.f, 0.f};
      s = MFMA_BF16(af0[i], b0, s);
      s = MFMA_BF16(af1[i], b1, s);
#pragma unroll
      for (int r = 0; r < 4; r++)
        l_acc[i * 4 + r] += exp2f(s[r] * cs);
    }
    if (kt < 31) {
      *(uint4*)&nxt[r0 * 72 + c0]        = ra;
      *(uint4*)&nxt[(r0 + 32) * 72 + c0] = rb;
    }
    __syncthreads();
  }

  // issue pass-2 prologue loads (kt=0 K and V) before the reduction work
  uint4 ka0, ka1, va0, va1;
  {
    ka0 = *(const uint4*)&Kg[(size_t)r0 * Dc + c0];
    ka1 = *(const uint4*)&Kg[(size_t)(r0 + 32) * Dc + c0];
    va0 = *(const uint4*)&Vg[(size_t)r0 * Sc + c0];
    va1 = *(const uint4*)&Vg[(size_t)(r0 + 32) * Sc + c0];
  }

  // reduce l over the 16 ln-lanes (deferred; once per kernel)
#pragma unroll
  for (int t = 0; t < 16; t++) {
    float v = l_acc[t];
    v += __shfl_xor(v, 1);
    v += __shfl_xor(v, 2);
    v += __shfl_xor(v, 4);
    v += __shfl_xor(v, 8);
    l_acc[t] = v;
  }
  if (ln == 0) {
#pragma unroll
    for (int i = 0; i < 4; i++)
#pragma unroll
      for (int r = 0; r < 4; r++)
        Lb[w][i * 16 + qd * 4 + r] = l_acc[i * 4 + r];
  }
  // stage kt=0: K -> buf1 (K ping), V -> buf0 (V ping; Q tile is dead)
  *(uint4*)&buf1[r0 * 72 + c0]        = ka0;
  *(uint4*)&buf1[(r0 + 32) * 72 + c0] = ka1;
  *(uint4*)&buf0[r0 * 72 + c0]        = va0;
  *(uint4*)&buf0[(r0 + 32) * 72 + c0] = va1;
  __syncthreads();

  float inv_l[4];
#pragma unroll
  for (int r = 0; r < 4; r++) {
    int row = w * 16 + qd * 4 + r;
    inv_l[r] = 1.f / (Lb[0][row] + Lb[1][row] + Lb[2][row] + Lb[3][row]);
  }

  f32x4 o[4];
#pragma unroll
  for (int j = 0; j < 4; j++) o[j] = f32x4{0.f, 0.f, 0.f, 0.f};
  float* a_base = a_out + ((size_t)bh * Sc + qb * 64) * Sc;
  u16* Pw = Ps + w * 16 * 72;

  // ---- pass 2: recompute scores, accumulate O = P@V, packed a-write ----
  // K: buf1 (even kt) / buf2 (odd kt);  V: buf0 (even) / buf3 (odd).
  // Read cur, write nxt -> ONE barrier per kt.
  for (int kt = 0; kt < 32; ++kt) {
    u16* Kcur = (kt & 1) ? buf2 : buf1;
    u16* Knxt = (kt & 1) ? buf1 : buf2;
    u16* Vcur = (kt & 1) ? buf3 : buf0;
    u16* Vnxt = (kt & 1) ? buf0 : buf3;
    uint4 ra0, ra1, rv0, rv1;
    if (kt < 31) {   // issue next-tile loads early
      const u16* Kt_ = Kg + (size_t)((kt + 1) * 64) * Dc;
      const u16* Vt_ = Vg + (kt + 1) * 64;
      ra0 = *(const uint4*)&Kt_[(size_t)r0 * Dc + c0];
      ra1 = *(const uint4*)&Kt_[(size_t)(r0 + 32) * Dc + c0];
      rv0 = *(const uint4*)&Vt_[(size_t)r0 * Sc + c0];
      rv1 = *(const uint4*)&Vt_[(size_t)(r0 + 32) * Sc + c0];
    }
    f32x4 s[4];
#pragma unroll
    for (int j = 0; j < 4; j++) {
      s[j] = f32x4{0.f, 0.f, 0.f, 0.f};
      bf16x8 b0 = *(const bf16x8*)&Kcur[(j * 16 + ln) * 72 + qd * 8];
      bf16x8 b1 = *(const bf16x8*)&Kcur[(j * 16 + ln) * 72 + 32 + qd * 8];
      s[j] = MFMA_BF16(qa0, b0, s[j]);
      s[j] = MFMA_BF16(qa1, b1, s[j]);
    }
    // normalized P -> per-wave LDS tile (bf16); feeds both PV and a-write
#pragma unroll
    for (int j = 0; j < 4; j++) {
#pragma unroll
      for (int r = 0; r < 4; r++) {
        float p = exp2f(s[j][r] * cs) * inv_l[r];
        Pw[(qd * 4 + r) * 72 + j * 16 + ln] = f32_to_bf16(p);
      }
    }
    // O += P @ V
    bf16x8 pa0 = *(const bf16x8*)&Pw[ln * 72 + qd * 8];
    bf16x8 pa1 = *(const bf16x8*)&Pw[ln * 72 + 32 + qd * 8];
#pragma unroll
    for (int j = 0; j < 4; j++) {
      bf16x8 vb0 = *(const bf16x8*)&Vcur[(j * 16 + ln) * 72 + qd * 8];
      bf16x8 vb1 = *(const bf16x8*)&Vcur[(j * 16 + ln) * 72 + 32 + qd * 8];
      o[j] = MFMA_BF16(pa0, vb0, o[j]);
      o[j] = MFMA_BF16(pa1, vb1, o[j]);
    }
    // packed a-write: re-read Pw as 4 bf16 chunks, store float4 (fully coalesced)
#pragma unroll
    for (int t = 0; t < 4; t++) {
      int chunk = lane + 64 * t;        // 0..255
      int row = chunk >> 4;             // 0..15
      int colc = (chunk & 15) * 4;      // 0..60
      u16 p4[4];
      *(uint2*)p4 = *(const uint2*)&Pw[row * 72 + colc];
      float4 f;
      f.x = bf16_to_f32(p4[0]); f.y = bf16_to_f32(p4[1]);
      f.z = bf16_to_f32(p4[2]); f.w = bf16_to_f32(p4[3]);
      *(float4*)&a_base[(size_t)(w * 16 + row) * Sc + kt * 64 + colc] = f;
    }
    // write staged next tiles into the opposite buffers, single barrier
    if (kt < 31) {
      *(uint4*)&Knxt[r0 * 72 + c0]        = ra0;
      *(uint4*)&Knxt[(r0 + 32) * 72 + c0] = ra1;
      *(uint4*)&Vnxt[r0 * 72 + c0]        = rv0;
      *(uint4*)&Vnxt[(r0 + 32) * 72 + c0] = rv1;
    }
    __syncthreads();
  }

  // write O (bf16) into [B,S,D] head-interleaved layout
  u16* Og = Oh + (size_t)(b * Sc + qb * 64) * Dc + h * 64;
#pragma unroll
  for (int j = 0; j < 4; j++)
#pragma unroll
    for (int r = 0; r < 4; r++)
      Og[(size_t)(w * 16 + qd * 4 + r) * Dc + j * 16 + ln] = f32_to_bf16(o[j][r]);
}

extern "C" void kernel_launch(void* const* d_in, const int* in_sizes, int n_in,
                              void* d_out, int out_size, void* d_ws, size_t ws_size,
                              hipStream_t stream)
{
  const float* q  = (const float*)d_in[0];
  const float* k  = (const float*)d_in[1];
  const float* v  = (const float*)d_in[2];
  const float* Wq = (const float*)d_in[3];
  const float* bq = (const float*)d_in[4];
  const float* Wk = (const float*)d_in[5];
  const float* bk = (const float*)d_in[6];
  const float* Wv = (const float*)d_in[7];
  const float* bv = (const float*)d_in[8];
  const float* Wo = (const float*)d_in[9];
  const float* bo = (const float*)d_in[10];

  u16* ws = (u16*)d_ws;
  u16* qb  = ws + OFF_QB;
  u16* kb  = ws + OFF_KB;
  u16* vb  = ws + OFF_VB;
  u16* Wqb = ws + OFF_WQB;
  u16* Wkb = ws + OFF_WKB;
  u16* Wvb = ws + OFF_WVB;
  u16* Wob = ws + OFF_WOB;
  u16* Qp  = ws + OFF_QP;
  u16* Kp  = ws + OFF_KP;
  u16* Vp  = ws + OFF_VP;
  u16* Vt  = ws + OFF_VT;
  u16* Oh  = ws + OFF_OH;

  float* out_o = (float*)d_out;                 // [2,2048,1024]
  float* out_a = out_o + 4194304;               // [2,16,2048,2048]

  cvt_all<<<dim3(2048, 7), 256, 0, stream>>>(q, k, v, Wq, Wk, Wv, Wo, ws);
  qkv_gemm<<<dim3(8, 32, 3), 256, 0, stream>>>(qb, kb, vb, Wqb, Wkb, Wvb, bq, bk, bv, Qp, Kp, Vp);
  transpose_v<<<dim3(32, 32), 256, 0, stream>>>(Vp, Vt);
  attn_kernel<<<dim3(32, 32), 256, 0, stream>>>(Qp, Kp, Vt, out_a, Oh);
  out_gemm<<<dim3(8, 32), 256, 0, stream>>>(Oh, Wob, bo, out_o);
}